// Round 18
// baseline (720.391 us; speedup 1.0000x reference)
//
#include <hip/hip_runtime.h>

typedef float f32x4 __attribute__((ext_vector_type(4)));
typedef unsigned int u32x4 __attribute__((ext_vector_type(4)));
typedef unsigned int u32x2 __attribute__((ext_vector_type(2)));

constexpr int   N     = 512;
constexpr int   NITER = 21;
constexpr float C2    = 144.26950408889634f;     // (1/T)*log2(e)

#define EXP2(x) __builtin_amdgcn_exp2f(x)
#define LOG2(x) __builtin_amdgcn_logf(x)
#define RCP(x)  __builtin_amdgcn_rcpf(x)

// ---- 24-bit fixed-point codec: q = (x+8)*2^20, 4 elems packed in 3 dwords --
__device__ __forceinline__ void pack3(const f32x4 v,
                                      unsigned& d0, unsigned& d1, unsigned& d2) {
    unsigned q0 = (unsigned)fminf(fmaxf(fmaf(v.x, 1048576.f, 8388608.f), 0.f), 16777215.f);
    unsigned q1 = (unsigned)fminf(fmaxf(fmaf(v.y, 1048576.f, 8388608.f), 0.f), 16777215.f);
    unsigned q2 = (unsigned)fminf(fmaxf(fmaf(v.z, 1048576.f, 8388608.f), 0.f), 16777215.f);
    unsigned q3 = (unsigned)fminf(fmaxf(fmaf(v.w, 1048576.f, 8388608.f), 0.f), 16777215.f);
    d0 = q0 | (q1 << 24);
    d1 = (q1 >> 8) | (q2 << 16);
    d2 = (q2 >> 16) | (q3 << 8);
}

__device__ __forceinline__ f32x4 unpack3(unsigned d0, unsigned d1, unsigned d2) {
    const float S = 9.5367431640625e-7f;   // 2^-20
    unsigned q0 = d0 & 0xFFFFFFu;
    unsigned q1 = (d0 >> 24) | ((d1 & 0xFFFFu) << 8);
    unsigned q2 = (d1 >> 16) | ((d2 & 0xFFu) << 16);
    unsigned q3 = d2 >> 8;
    f32x4 r;
    r.x = fmaf((float)q0, S, -8.0f);
    r.y = fmaf((float)q1, S, -8.0f);
    r.z = fmaf((float)q2, S, -8.0f);
    r.w = fmaf((float)q3, S, -8.0f);
    return r;
}

// R15's proven proc4: 4-row group, ONE exp2 per element per iteration;
// e overwrites x in place (x dead once e exists); column pass cac += e*rcp(s).
// R16's magnitude-shifted variant (ush+8*C2 folding) FAILED numerically:
// log-domain state must stay in its small-magnitude regime.
template<bool FIRST>
__device__ __forceinline__ void proc4(f32x4* xa, f32x4* xc,
                                      const float* vl, float* cac,
                                      float* u_s, int rbase, int lane) {
    float ush[4];
    if (FIRST) {
        #pragma unroll
        for (int r = 0; r < 4; ++r) {
            float m0 = fmaxf(fmaxf(xa[r].x, xa[r].y), fmaxf(xa[r].z, xa[r].w));
            float m1 = fmaxf(fmaxf(xc[r].x, xc[r].y), fmaxf(xc[r].z, xc[r].w));
            ush[r] = fmaxf(m0, m1) * C2;
        }
        #pragma unroll
        for (int off = 32; off > 0; off >>= 1)
            #pragma unroll
            for (int r = 0; r < 4; ++r)
                ush[r] = fmaxf(ush[r], __shfl_xor(ush[r], off, 64));
    } else {
        #pragma unroll
        for (int r = 0; r < 4; ++r) ush[r] = u_s[rbase + r];
    }

    float s[4];
    #pragma unroll
    for (int r = 0; r < 4; ++r) {
        float s0 = 0.f, s1 = 0.f;
        #pragma unroll
        for (int k = 0; k < 4; ++k) {
            const float ea = EXP2(fmaf(xa[r][k], C2, -(vl[k]     + ush[r])));
            const float ec = EXP2(fmaf(xc[r][k], C2, -(vl[4 + k] + ush[r])));
            xa[r][k] = ea;          // e overwrites x (x dead from here)
            xc[r][k] = ec;
            s0 += ea; s1 += ec;
        }
        s[r] = s0 + s1;
    }
    #pragma unroll
    for (int off = 32; off > 0; off >>= 1)
        #pragma unroll
        for (int r = 0; r < 4; ++r)
            s[r] += __shfl_xor(s[r], off, 64);
    #pragma unroll
    for (int r = 0; r < 4; ++r) {
        const float sc = fmaxf(s[r], 1e-37f);
        const float a  = RCP(sc);            // exp2(ush - u_new)
        if (lane == 0) u_s[rbase + r] = ush[r] + LOG2(sc);
        #pragma unroll
        for (int k = 0; k < 4; ++k) {
            cac[k]     = fmaf(xa[r][k], a, cac[k]);
            cac[4 + k] = fmaf(xc[r][k], a, cac[4 + k]);
        }
    }
}

__device__ __forceinline__ void out4(const f32x4* xa, const f32x4* xc,
                                     const float* vl, const float* u_s,
                                     int rbase, float* ob, int j0) {
    #pragma unroll
    for (int r = 0; r < 4; ++r) {
        const float ush = u_s[rbase + r];
        float ov[8];
        #pragma unroll
        for (int k = 0; k < 4; ++k) {
            ov[k]     = EXP2(fmaf(xa[r][k], C2, -(vl[k]     + ush)));
            ov[4 + k] = EXP2(fmaf(xc[r][k], C2, -(vl[4 + k] + ush)));
        }
        float* orow = ob + (size_t)(rbase + r) * N;
        __builtin_nontemporal_store((f32x4){ov[0],ov[1],ov[2],ov[3]},
                                    (f32x4*)(orow + j0));
        __builtin_nontemporal_store((f32x4){ov[4],ov[5],ov[6],ov[7]},
                                    (f32x4*)(orow + 256 + j0));
    }
}

// 1 block per matrix, 1024 threads = 16 waves.
// wave w owns rows [32w,32w+32); lane owns cols {4l..4l+3, 256+4l..259+4l}.
// Residency: rows 0-3 VGPR archive (group 0), rows 4-7 LDS stage (group 1).
// Rows 8-31 (groups 2-7): packed 24-bit in this block's d_out slot (written
// iter 0), re-read compressed iters 1-20. Output reads ORIGINAL x (NT).
// R17 = R15 numerics (proven absmax 0.0117) + R16's atomic column reduce
// (ds_add_f32 into cacc[512], 2 barriers/iter instead of 3; ordering noise
// ~1e-6 relative, far below the 2e-2 threshold).
__global__ void
__launch_bounds__(1024, 4)
sinkhorn_kernel(const float* __restrict__ x, float* __restrict__ out) {
    __shared__ alignas(16) float stage[64][N];   // 128 KiB: 4 rows/wave (raw x)
    __shared__ float u_s[N];                     // row potentials (base-2)
    __shared__ alignas(16) float v_s[N];         // col potentials (base-2)
    __shared__ alignas(16) float cacc[N];        //  2 KiB atomic col sums

    const int tid  = threadIdx.x;
    const int wave = tid >> 6;
    const int lane = tid & 63;
    const int j0   = lane << 2;
    const int srot2 = ((wave >> 2) & 3) << 1;    // within-SIMD stagger: 0,2,4,6

    const size_t base = (size_t)blockIdx.x * (size_t)(N * N);
    const float* __restrict__ xb = x + base;
    const int row0 = wave * 32;
    const int sb   = wave * 4;       // this wave's LDS stage base row
    const int w24  = wave * 24;      // compressed rows per wave
    const int lane24 = lane * 24;
    unsigned char* cb = (unsigned char*)(out + base);   // compressed region

// nontemporal fp32 4-row load (x is single-use streaming data)
#define LOAD4(g, XA, XC)                                                \
    _Pragma("unroll")                                                   \
    for (int r_ = 0; r_ < 4; ++r_) {                                    \
        const float* row_ = xb + (size_t)(row0 + (g) * 4 + r_) * N;     \
        XA[r_] = __builtin_nontemporal_load((const f32x4*)(row_ + j0)); \
        XC[r_] = __builtin_nontemporal_load((const f32x4*)(row_ + 256 + j0)); \
    }

#define PACK4(g, XA, XC)                                                \
    _Pragma("unroll")                                                   \
    for (int r_ = 0; r_ < 4; ++r_) {                                    \
        unsigned char* p_ = cb + (size_t)(w24 + (g) * 4 - 8 + r_) * 1536 + lane24; \
        unsigned a0_, a1_, a2_, c0_, c1_, c2_;                          \
        pack3(XA[r_], a0_, a1_, a2_);                                   \
        pack3(XC[r_], c0_, c1_, c2_);                                   \
        *(u32x4*)p_        = (u32x4){a0_, a1_, a2_, c0_};               \
        *(u32x2*)(p_ + 16) = (u32x2){c1_, c2_};                         \
    }

#define LOAD4C(g, XA, XC)                                               \
    _Pragma("unroll")                                                   \
    for (int r_ = 0; r_ < 4; ++r_) {                                    \
        const unsigned char* p_ = cb + (size_t)(w24 + (g) * 4 - 8 + r_) * 1536 + lane24; \
        const u32x4 d4_ = *(const u32x4*)p_;                            \
        const u32x2 d2_ = *(const u32x2*)(p_ + 16);                     \
        XA[r_] = unpack3(d4_.x, d4_.y, d4_.z);                          \
        XC[r_] = unpack3(d4_.w, d2_.x, d2_.y);                          \
    }

#define ARCH4(XA, XC)                                                   \
    _Pragma("unroll")                                                   \
    for (int r_ = 0; r_ < 4; ++r_) { XA[r_] = aA[r_]; XC[r_] = aC[r_]; }

#define STAGE4(XA, XC)                                                  \
    _Pragma("unroll")                                                   \
    for (int r_ = 0; r_ < 4; ++r_) {                                    \
        XA[r_] = *(const f32x4*)&stage[sb + r_][j0];                    \
        XC[r_] = *(const f32x4*)&stage[sb + r_][256 + j0];              \
    }

// atomic column reduce: per-lane posts, one barrier, v-update + reset
#define COLREDUCE()                                                      \
    { _Pragma("unroll")                                                  \
      for (int k_ = 0; k_ < 4; ++k_) {                                   \
          unsafeAtomicAdd(&cacc[j0 + k_],       cac[k_]);                \
          unsafeAtomicAdd(&cacc[256 + j0 + k_], cac[4 + k_]);            \
      }                                                                  \
      __syncthreads();                                                   \
      if (tid < N) {                                                     \
          const float ss = cacc[tid];                                    \
          v_s[tid] += LOG2(fmaxf(ss, 1e-37f));                           \
          cacc[tid] = 0.f;                                               \
      }                                                                  \
      __syncthreads(); }

    f32x4 aA[4], aC[4];            // VGPR archive: rows row0+0..3 (raw x)

    if (tid < N) { u_s[tid] = 0.0f; v_s[tid] = 0.0f; cacc[tid] = 0.0f; }
    __syncthreads();

    // --- iteration 0: full fp32 read (NT); fill archive/stage; emit packed --
    {
        const float vz[8] = {0.f,0.f,0.f,0.f,0.f,0.f,0.f,0.f};
        float cac[8] = {0.f,0.f,0.f,0.f,0.f,0.f,0.f,0.f};
        f32x4 xa[4], xc[4];
        LOAD4(0, xa, xc)
        #pragma unroll
        for (int r = 0; r < 4; ++r) { aA[r] = xa[r]; aC[r] = xc[r]; }
        proc4<true>(xa, xc, vz, cac, u_s, row0, lane);
        LOAD4(1, xa, xc)
        #pragma unroll
        for (int r = 0; r < 4; ++r) {
            *(f32x4*)&stage[sb + r][j0]       = xa[r];
            *(f32x4*)&stage[sb + r][256 + j0] = xc[r];
        }
        proc4<true>(xa, xc, vz, cac, u_s, row0 + 4, lane);
        #pragma unroll 1
        for (int g = 2; g < 8; ++g) {
            LOAD4(g, xa, xc)
            PACK4(g, xa, xc)
            proc4<true>(xa, xc, vz, cac, u_s, row0 + g * 4, lane);
        }
        COLREDUCE()
    }

    // --- iterations 1..20: resident + compressed re-read, SIMD-staggered ----
    #pragma unroll 1
    for (int it = 1; it < NITER; ++it) {
        const f32x4 va = *(const f32x4*)&v_s[j0];
        const f32x4 vb = *(const f32x4*)&v_s[256 + j0];
        const float vl[8] = {va.x, va.y, va.z, va.w, vb.x, vb.y, vb.z, vb.w};
        float cac[8] = {0.f,0.f,0.f,0.f,0.f,0.f,0.f,0.f};
        f32x4 xa[4], xc[4];

        #pragma unroll 1
        for (int p = 0; p < 8; ++p) {
            const int g = (p + srot2) & 7;   // wave-uniform branch
            if (g == 0) {
                ARCH4(xa, xc)
                proc4<false>(xa, xc, vl, cac, u_s, row0, lane);
            } else if (g == 1) {
                STAGE4(xa, xc)
                proc4<false>(xa, xc, vl, cac, u_s, row0 + 4, lane);
            } else {
                LOAD4C(g, xa, xc)
                proc4<false>(xa, xc, vl, cac, u_s, row0 + g * 4, lane);
            }
        }
        COLREDUCE()
    }

    // --- output: exp2(x*C2 - u - v) from ORIGINAL x (NT); overwrites slot ---
    {
        const f32x4 va = *(const f32x4*)&v_s[j0];
        const f32x4 vb = *(const f32x4*)&v_s[256 + j0];
        const float vl[8] = {va.x, va.y, va.z, va.w, vb.x, vb.y, vb.z, vb.w};
        float* __restrict__ ob = out + base;
        f32x4 xa[4], xc[4];
        #pragma unroll 1
        for (int p = 0; p < 8; ++p) {
            const int g = (p + srot2) & 7;
            if (g == 0) {
                ARCH4(xa, xc)
                out4(xa, xc, vl, u_s, row0, ob, j0);
            } else if (g == 1) {
                STAGE4(xa, xc)
                out4(xa, xc, vl, u_s, row0 + 4, ob, j0);
            } else {
                LOAD4(g, xa, xc)
                out4(xa, xc, vl, u_s, row0 + g * 4, ob, j0);
            }
        }
    }
}

extern "C" void kernel_launch(void* const* d_in, const int* in_sizes, int n_in,
                              void* d_out, int out_size, void* d_ws, size_t ws_size,
                              hipStream_t stream) {
    const float* x = (const float*)d_in[0];
    float* out = (float*)d_out;
    const int nmat = in_sizes[0] / (N * N);   // 256
    sinkhorn_kernel<<<nmat, 1024, 0, stream>>>(x, out);
}

// Round 19
// 556.141 us; speedup vs baseline: 1.2953x; 1.2953x over previous
//
#include <hip/hip_runtime.h>

typedef float f32x4 __attribute__((ext_vector_type(4)));
typedef unsigned int u32x4 __attribute__((ext_vector_type(4)));
typedef unsigned int u32x2 __attribute__((ext_vector_type(2)));

constexpr int   N     = 512;
constexpr int   NITER = 21;
constexpr float C2    = 144.26950408889634f;     // (1/T)*log2(e)

#define EXP2(x) __builtin_amdgcn_exp2f(x)
#define LOG2(x) __builtin_amdgcn_logf(x)
#define RCP(x)  __builtin_amdgcn_rcpf(x)

// ---- 24-bit fixed-point codec: q = (x+8)*2^20, 4 elems packed in 3 dwords --
__device__ __forceinline__ void pack3(const f32x4 v,
                                      unsigned& d0, unsigned& d1, unsigned& d2) {
    unsigned q0 = (unsigned)fminf(fmaxf(fmaf(v.x, 1048576.f, 8388608.f), 0.f), 16777215.f);
    unsigned q1 = (unsigned)fminf(fmaxf(fmaf(v.y, 1048576.f, 8388608.f), 0.f), 16777215.f);
    unsigned q2 = (unsigned)fminf(fmaxf(fmaf(v.z, 1048576.f, 8388608.f), 0.f), 16777215.f);
    unsigned q3 = (unsigned)fminf(fmaxf(fmaf(v.w, 1048576.f, 8388608.f), 0.f), 16777215.f);
    d0 = q0 | (q1 << 24);
    d1 = (q1 >> 8) | (q2 << 16);
    d2 = (q2 >> 16) | (q3 << 8);
}

__device__ __forceinline__ f32x4 unpack3(unsigned d0, unsigned d1, unsigned d2) {
    const float S = 9.5367431640625e-7f;   // 2^-20
    unsigned q0 = d0 & 0xFFFFFFu;
    unsigned q1 = (d0 >> 24) | ((d1 & 0xFFFFu) << 8);
    unsigned q2 = (d1 >> 16) | ((d2 & 0xFFu) << 16);
    unsigned q3 = d2 >> 8;
    f32x4 r;
    r.x = fmaf((float)q0, S, -8.0f);
    r.y = fmaf((float)q1, S, -8.0f);
    r.z = fmaf((float)q2, S, -8.0f);
    r.w = fmaf((float)q3, S, -8.0f);
    return r;
}

// R15's proven proc4: 4-row group, ONE exp2 per element per iteration;
// e overwrites x in place (x dead once e exists); column pass cac += e*rcp(s).
// Live set ~56 regs -> fits the hard 64-VGPR cap without spill.
template<bool FIRST>
__device__ __forceinline__ void proc4(f32x4* xa, f32x4* xc,
                                      const float* vl, float* cac,
                                      float* u_s, int rbase, int lane) {
    float ush[4];
    if (FIRST) {
        #pragma unroll
        for (int r = 0; r < 4; ++r) {
            float m0 = fmaxf(fmaxf(xa[r].x, xa[r].y), fmaxf(xa[r].z, xa[r].w));
            float m1 = fmaxf(fmaxf(xc[r].x, xc[r].y), fmaxf(xc[r].z, xc[r].w));
            ush[r] = fmaxf(m0, m1) * C2;
        }
        #pragma unroll
        for (int off = 32; off > 0; off >>= 1)
            #pragma unroll
            for (int r = 0; r < 4; ++r)
                ush[r] = fmaxf(ush[r], __shfl_xor(ush[r], off, 64));
    } else {
        #pragma unroll
        for (int r = 0; r < 4; ++r) ush[r] = u_s[rbase + r];
    }

    float s[4];
    #pragma unroll
    for (int r = 0; r < 4; ++r) {
        float s0 = 0.f, s1 = 0.f;
        #pragma unroll
        for (int k = 0; k < 4; ++k) {
            const float ea = EXP2(fmaf(xa[r][k], C2, -(vl[k]     + ush[r])));
            const float ec = EXP2(fmaf(xc[r][k], C2, -(vl[4 + k] + ush[r])));
            xa[r][k] = ea;          // e overwrites x (x dead from here)
            xc[r][k] = ec;
            s0 += ea; s1 += ec;
        }
        s[r] = s0 + s1;
    }
    #pragma unroll
    for (int off = 32; off > 0; off >>= 1)
        #pragma unroll
        for (int r = 0; r < 4; ++r)
            s[r] += __shfl_xor(s[r], off, 64);
    #pragma unroll
    for (int r = 0; r < 4; ++r) {
        const float sc = fmaxf(s[r], 1e-37f);
        const float a  = RCP(sc);            // exp2(ush - u_new)
        if (lane == 0) u_s[rbase + r] = ush[r] + LOG2(sc);
        #pragma unroll
        for (int k = 0; k < 4; ++k) {
            cac[k]     = fmaf(xa[r][k], a, cac[k]);
            cac[4 + k] = fmaf(xc[r][k], a, cac[4 + k]);
        }
    }
}

__device__ __forceinline__ void out4(const f32x4* xa, const f32x4* xc,
                                     const float* vl, const float* u_s,
                                     int rbase, float* ob, int j0) {
    #pragma unroll
    for (int r = 0; r < 4; ++r) {
        const float ush = u_s[rbase + r];
        float ov[8];
        #pragma unroll
        for (int k = 0; k < 4; ++k) {
            ov[k]     = EXP2(fmaf(xa[r][k], C2, -(vl[k]     + ush)));
            ov[4 + k] = EXP2(fmaf(xc[r][k], C2, -(vl[4 + k] + ush)));
        }
        float* orow = ob + (size_t)(rbase + r) * N;
        __builtin_nontemporal_store((f32x4){ov[0],ov[1],ov[2],ov[3]},
                                    (f32x4*)(orow + j0));
        __builtin_nontemporal_store((f32x4){ov[4],ov[5],ov[6],ov[7]},
                                    (f32x4*)(orow + 256 + j0));
    }
}

// 1 block per matrix, 1024 threads = 16 waves. (R15, the proven optimum.)
// wave w owns rows [32w,32w+32); lane owns cols {4l..4l+3, 256+4l..259+4l}.
// Residency: rows 0-3 VGPR archive (group 0), rows 4-7 LDS stage (group 1).
// Rows 8-31 (groups 2-7): packed 24-bit in this block's d_out slot (written
// iter 0), re-read compressed iters 1-20 (144 MiB chip-wide, L3-resident).
// Output reads ORIGINAL x (NT) and overwrites the slot.
// Column reduce: cpart8 vectorized ladder, 3 barriers (R17 proved LDS-atomic
// 2-barrier version is 30% slower: 16 serialized ds_add_f32 per address).
__global__ void
__launch_bounds__(1024, 4)
sinkhorn_kernel(const float* __restrict__ x, float* __restrict__ out) {
    __shared__ alignas(16) float stage[64][N];   // 128 KiB: 4 rows/wave (raw x)
    __shared__ alignas(16) float cpart8[8][N];   //  16 KiB: 2-phase col partials
    __shared__ float u_s[N];                     // row potentials (base-2)
    __shared__ alignas(16) float v_s[N];         // col potentials (base-2)

    const int tid  = threadIdx.x;
    const int wave = tid >> 6;
    const int lane = tid & 63;
    const int j0   = lane << 2;
    const int srot2 = ((wave >> 2) & 3) << 1;    // within-SIMD stagger: 0,2,4,6

    const size_t base = (size_t)blockIdx.x * (size_t)(N * N);
    const float* __restrict__ xb = x + base;
    const int row0 = wave * 32;
    const int sb   = wave * 4;       // this wave's LDS stage base row
    const int w24  = wave * 24;      // compressed rows per wave
    const int lane24 = lane * 24;
    unsigned char* cb = (unsigned char*)(out + base);   // compressed region

// nontemporal fp32 4-row load (x is single-use streaming data)
#define LOAD4(g, XA, XC)                                                \
    _Pragma("unroll")                                                   \
    for (int r_ = 0; r_ < 4; ++r_) {                                    \
        const float* row_ = xb + (size_t)(row0 + (g) * 4 + r_) * N;     \
        XA[r_] = __builtin_nontemporal_load((const f32x4*)(row_ + j0)); \
        XC[r_] = __builtin_nontemporal_load((const f32x4*)(row_ + 256 + j0)); \
    }

#define PACK4(g, XA, XC)                                                \
    _Pragma("unroll")                                                   \
    for (int r_ = 0; r_ < 4; ++r_) {                                    \
        unsigned char* p_ = cb + (size_t)(w24 + (g) * 4 - 8 + r_) * 1536 + lane24; \
        unsigned a0_, a1_, a2_, c0_, c1_, c2_;                          \
        pack3(XA[r_], a0_, a1_, a2_);                                   \
        pack3(XC[r_], c0_, c1_, c2_);                                   \
        *(u32x4*)p_        = (u32x4){a0_, a1_, a2_, c0_};               \
        *(u32x2*)(p_ + 16) = (u32x2){c1_, c2_};                         \
    }

#define LOAD4C(g, XA, XC)                                               \
    _Pragma("unroll")                                                   \
    for (int r_ = 0; r_ < 4; ++r_) {                                    \
        const unsigned char* p_ = cb + (size_t)(w24 + (g) * 4 - 8 + r_) * 1536 + lane24; \
        const u32x4 d4_ = *(const u32x4*)p_;                            \
        const u32x2 d2_ = *(const u32x2*)(p_ + 16);                     \
        XA[r_] = unpack3(d4_.x, d4_.y, d4_.z);                          \
        XC[r_] = unpack3(d4_.w, d2_.x, d2_.y);                          \
    }

#define ARCH4(XA, XC)                                                   \
    _Pragma("unroll")                                                   \
    for (int r_ = 0; r_ < 4; ++r_) { XA[r_] = aA[r_]; XC[r_] = aC[r_]; }

#define STAGE4(XA, XC)                                                  \
    _Pragma("unroll")                                                   \
    for (int r_ = 0; r_ < 4; ++r_) {                                    \
        XA[r_] = *(const f32x4*)&stage[sb + r_][j0];                    \
        XC[r_] = *(const f32x4*)&stage[sb + r_][256 + j0];              \
    }

#define COLREDUCE()                                                      \
    { if (wave < 8) {                                                    \
          *(f32x4*)&cpart8[wave][j0]       = (f32x4){cac[0],cac[1],cac[2],cac[3]}; \
          *(f32x4*)&cpart8[wave][256 + j0] = (f32x4){cac[4],cac[5],cac[6],cac[7]}; \
      }                                                                  \
      __syncthreads();                                                   \
      if (wave >= 8) {                                                   \
          f32x4 t0 = *(f32x4*)&cpart8[wave - 8][j0];                     \
          f32x4 t1 = *(f32x4*)&cpart8[wave - 8][256 + j0];               \
          t0 += (f32x4){cac[0],cac[1],cac[2],cac[3]};                    \
          t1 += (f32x4){cac[4],cac[5],cac[6],cac[7]};                    \
          *(f32x4*)&cpart8[wave - 8][j0]       = t0;                     \
          *(f32x4*)&cpart8[wave - 8][256 + j0] = t1;                     \
      }                                                                  \
      __syncthreads();                                                   \
      if (tid < N) {                                                     \
          float ss = 0.f;                                                \
          _Pragma("unroll")                                              \
          for (int p = 0; p < 8; ++p) ss += cpart8[p][tid];              \
          v_s[tid] += LOG2(fmaxf(ss, 1e-37f));                           \
      }                                                                  \
      __syncthreads(); }

    f32x4 aA[4], aC[4];            // VGPR archive: rows row0+0..3 (raw x)

    if (tid < N) { u_s[tid] = 0.0f; v_s[tid] = 0.0f; }
    __syncthreads();

    // --- iteration 0: full fp32 read (NT); fill archive/stage; emit packed --
    {
        const float vz[8] = {0.f,0.f,0.f,0.f,0.f,0.f,0.f,0.f};
        float cac[8] = {0.f,0.f,0.f,0.f,0.f,0.f,0.f,0.f};
        f32x4 xa[4], xc[4];
        LOAD4(0, xa, xc)
        #pragma unroll
        for (int r = 0; r < 4; ++r) { aA[r] = xa[r]; aC[r] = xc[r]; }
        proc4<true>(xa, xc, vz, cac, u_s, row0, lane);
        LOAD4(1, xa, xc)
        #pragma unroll
        for (int r = 0; r < 4; ++r) {
            *(f32x4*)&stage[sb + r][j0]       = xa[r];
            *(f32x4*)&stage[sb + r][256 + j0] = xc[r];
        }
        proc4<true>(xa, xc, vz, cac, u_s, row0 + 4, lane);
        #pragma unroll 1
        for (int g = 2; g < 8; ++g) {
            LOAD4(g, xa, xc)
            PACK4(g, xa, xc)
            proc4<true>(xa, xc, vz, cac, u_s, row0 + g * 4, lane);
        }
        COLREDUCE()
    }

    // --- iterations 1..20: resident + compressed re-read, SIMD-staggered ----
    #pragma unroll 1
    for (int it = 1; it < NITER; ++it) {
        const f32x4 va = *(const f32x4*)&v_s[j0];
        const f32x4 vb = *(const f32x4*)&v_s[256 + j0];
        const float vl[8] = {va.x, va.y, va.z, va.w, vb.x, vb.y, vb.z, vb.w};
        float cac[8] = {0.f,0.f,0.f,0.f,0.f,0.f,0.f,0.f};
        f32x4 xa[4], xc[4];

        #pragma unroll 1
        for (int p = 0; p < 8; ++p) {
            const int g = (p + srot2) & 7;   // wave-uniform branch
            if (g == 0) {
                ARCH4(xa, xc)
                proc4<false>(xa, xc, vl, cac, u_s, row0, lane);
            } else if (g == 1) {
                STAGE4(xa, xc)
                proc4<false>(xa, xc, vl, cac, u_s, row0 + 4, lane);
            } else {
                LOAD4C(g, xa, xc)
                proc4<false>(xa, xc, vl, cac, u_s, row0 + g * 4, lane);
            }
        }
        COLREDUCE()
    }

    // --- output: exp2(x*C2 - u - v) from ORIGINAL x (NT); overwrites slot ---
    {
        const f32x4 va = *(const f32x4*)&v_s[j0];
        const f32x4 vb = *(const f32x4*)&v_s[256 + j0];
        const float vl[8] = {va.x, va.y, va.z, va.w, vb.x, vb.y, vb.z, vb.w};
        float* __restrict__ ob = out + base;
        f32x4 xa[4], xc[4];
        #pragma unroll 1
        for (int p = 0; p < 8; ++p) {
            const int g = (p + srot2) & 7;
            if (g == 0) {
                ARCH4(xa, xc)
                out4(xa, xc, vl, u_s, row0, ob, j0);
            } else if (g == 1) {
                STAGE4(xa, xc)
                out4(xa, xc, vl, u_s, row0 + 4, ob, j0);
            } else {
                LOAD4(g, xa, xc)
                out4(xa, xc, vl, u_s, row0 + g * 4, ob, j0);
            }
        }
    }
}

extern "C" void kernel_launch(void* const* d_in, const int* in_sizes, int n_in,
                              void* d_out, int out_size, void* d_ws, size_t ws_size,
                              hipStream_t stream) {
    const float* x = (const float*)d_in[0];
    float* out = (float*)d_out;
    const int nmat = in_sizes[0] / (N * N);   // 256
    sinkhorn_kernel<<<nmat, 1024, 0, stream>>>(x, out);
}

// Round 20
// 533.876 us; speedup vs baseline: 1.3494x; 1.0417x over previous
//
#include <hip/hip_runtime.h>

typedef float f32x4 __attribute__((ext_vector_type(4)));
typedef unsigned int u32x4 __attribute__((ext_vector_type(4)));
typedef unsigned int u32x2 __attribute__((ext_vector_type(2)));

constexpr int   N     = 512;
constexpr int   NITER = 21;
constexpr float C2    = 144.26950408889634f;     // (1/T)*log2(e)

#define EXP2(x) __builtin_amdgcn_exp2f(x)
#define LOG2(x) __builtin_amdgcn_logf(x)
#define RCP(x)  __builtin_amdgcn_rcpf(x)

// ---- 24-bit fixed-point codec: q = (x+8)*2^20, 4 elems packed in 3 dwords --
__device__ __forceinline__ void pack3(const f32x4 v,
                                      unsigned& d0, unsigned& d1, unsigned& d2) {
    unsigned q0 = (unsigned)fminf(fmaxf(fmaf(v.x, 1048576.f, 8388608.f), 0.f), 16777215.f);
    unsigned q1 = (unsigned)fminf(fmaxf(fmaf(v.y, 1048576.f, 8388608.f), 0.f), 16777215.f);
    unsigned q2 = (unsigned)fminf(fmaxf(fmaf(v.z, 1048576.f, 8388608.f), 0.f), 16777215.f);
    unsigned q3 = (unsigned)fminf(fmaxf(fmaf(v.w, 1048576.f, 8388608.f), 0.f), 16777215.f);
    d0 = q0 | (q1 << 24);
    d1 = (q1 >> 8) | (q2 << 16);
    d2 = (q2 >> 16) | (q3 << 8);
}

__device__ __forceinline__ f32x4 unpack3(unsigned d0, unsigned d1, unsigned d2) {
    const float S = 9.5367431640625e-7f;   // 2^-20
    unsigned q0 = d0 & 0xFFFFFFu;
    unsigned q1 = (d0 >> 24) | ((d1 & 0xFFFFu) << 8);
    unsigned q2 = (d1 >> 16) | ((d2 & 0xFFu) << 16);
    unsigned q3 = d2 >> 8;
    f32x4 r;
    r.x = fmaf((float)q0, S, -8.0f);
    r.y = fmaf((float)q1, S, -8.0f);
    r.z = fmaf((float)q2, S, -8.0f);
    r.w = fmaf((float)q3, S, -8.0f);
    return r;
}

// R15's proven proc4: 4-row group, ONE exp2 per element per iteration;
// e overwrites x in place; column pass cac += e*rcp(s). ~56 live regs.
template<bool FIRST>
__device__ __forceinline__ void proc4(f32x4* xa, f32x4* xc,
                                      const float* vl, float* cac,
                                      float* u_s, int rbase, int lane) {
    float ush[4];
    if (FIRST) {
        #pragma unroll
        for (int r = 0; r < 4; ++r) {
            float m0 = fmaxf(fmaxf(xa[r].x, xa[r].y), fmaxf(xa[r].z, xa[r].w));
            float m1 = fmaxf(fmaxf(xc[r].x, xc[r].y), fmaxf(xc[r].z, xc[r].w));
            ush[r] = fmaxf(m0, m1) * C2;
        }
        #pragma unroll
        for (int off = 32; off > 0; off >>= 1)
            #pragma unroll
            for (int r = 0; r < 4; ++r)
                ush[r] = fmaxf(ush[r], __shfl_xor(ush[r], off, 64));
    } else {
        #pragma unroll
        for (int r = 0; r < 4; ++r) ush[r] = u_s[rbase + r];
    }

    float s[4];
    #pragma unroll
    for (int r = 0; r < 4; ++r) {
        float s0 = 0.f, s1 = 0.f;
        #pragma unroll
        for (int k = 0; k < 4; ++k) {
            const float ea = EXP2(fmaf(xa[r][k], C2, -(vl[k]     + ush[r])));
            const float ec = EXP2(fmaf(xc[r][k], C2, -(vl[4 + k] + ush[r])));
            xa[r][k] = ea;          // e overwrites x (x dead from here)
            xc[r][k] = ec;
            s0 += ea; s1 += ec;
        }
        s[r] = s0 + s1;
    }
    #pragma unroll
    for (int off = 32; off > 0; off >>= 1)
        #pragma unroll
        for (int r = 0; r < 4; ++r)
            s[r] += __shfl_xor(s[r], off, 64);
    #pragma unroll
    for (int r = 0; r < 4; ++r) {
        const float sc = fmaxf(s[r], 1e-37f);
        const float a  = RCP(sc);            // exp2(ush - u_new)
        if (lane == 0) u_s[rbase + r] = ush[r] + LOG2(sc);
        #pragma unroll
        for (int k = 0; k < 4; ++k) {
            cac[k]     = fmaf(xa[r][k], a, cac[k]);
            cac[4 + k] = fmaf(xc[r][k], a, cac[4 + k]);
        }
    }
}

__device__ __forceinline__ void out4(const f32x4* xa, const f32x4* xc,
                                     const float* vl, const float* u_s,
                                     int rbase, float* ob, int j0) {
    #pragma unroll
    for (int r = 0; r < 4; ++r) {
        const float ush = u_s[rbase + r];
        float ov[8];
        #pragma unroll
        for (int k = 0; k < 4; ++k) {
            ov[k]     = EXP2(fmaf(xa[r][k], C2, -(vl[k]     + ush)));
            ov[4 + k] = EXP2(fmaf(xc[r][k], C2, -(vl[4 + k] + ush)));
        }
        float* orow = ob + (size_t)(rbase + r) * N;
        __builtin_nontemporal_store((f32x4){ov[0],ov[1],ov[2],ov[3]},
                                    (f32x4*)(orow + j0));
        __builtin_nontemporal_store((f32x4){ov[4],ov[5],ov[6],ov[7]},
                                    (f32x4*)(orow + 256 + j0));
    }
}

// 1 block per matrix, 1024 threads = 16 waves.
// wave w owns rows [32w,32w+32); lane owns cols {4l..4l+3, 256+4l..259+4l}.
// Residency: rows 0-3 VGPR archive (g0), rows 4-7 LDS stage (g1).
// Rows 8-31 (g2-7): packed 24-bit INSIDE this wave's own 64 KiB output
// window (cb + row0*2048; 36 KiB of 64), written iter 0, re-read iters 1-20.
// R19: the output pass computes g2-7 FROM the compressed data (descending
// group order g7->g2 makes every output write land only on already-consumed
// compressed bytes - verified byte-exact, pure within-wave WAR, no barriers)
// -> the 256 MiB fp32 x re-read in the output pass is eliminated.
__global__ void
__launch_bounds__(1024, 4)
sinkhorn_kernel(const float* __restrict__ x, float* __restrict__ out) {
    __shared__ alignas(16) float stage[64][N];   // 128 KiB: 4 rows/wave (raw x)
    __shared__ alignas(16) float cpart8[8][N];   //  16 KiB: 2-phase col partials
    __shared__ float u_s[N];                     // row potentials (base-2)
    __shared__ alignas(16) float v_s[N];         // col potentials (base-2)

    const int tid  = threadIdx.x;
    const int wave = tid >> 6;
    const int lane = tid & 63;
    const int j0   = lane << 2;
    const int srot2 = ((wave >> 2) & 3) << 1;    // within-SIMD stagger: 0,2,4,6

    const size_t base = (size_t)blockIdx.x * (size_t)(N * N);
    const float* __restrict__ xb = x + base;
    const int row0 = wave * 32;
    const int sb   = wave * 4;       // this wave's LDS stage base row
    const int lane24 = lane * 24;
    // compressed region: wave's OWN output window (rows row0..row0+31)
    unsigned char* cb = (unsigned char*)(out + base) + (size_t)row0 * 2048;

// nontemporal fp32 4-row load (x is single-use streaming data)
#define LOAD4(g, XA, XC)                                                \
    _Pragma("unroll")                                                   \
    for (int r_ = 0; r_ < 4; ++r_) {                                    \
        const float* row_ = xb + (size_t)(row0 + (g) * 4 + r_) * N;     \
        XA[r_] = __builtin_nontemporal_load((const f32x4*)(row_ + j0)); \
        XC[r_] = __builtin_nontemporal_load((const f32x4*)(row_ + 256 + j0)); \
    }

#define PACK4(g, XA, XC)                                                \
    _Pragma("unroll")                                                   \
    for (int r_ = 0; r_ < 4; ++r_) {                                    \
        unsigned char* p_ = cb + (size_t)((g) * 4 - 8 + r_) * 1536 + lane24; \
        unsigned a0_, a1_, a2_, c0_, c1_, c2_;                          \
        pack3(XA[r_], a0_, a1_, a2_);                                   \
        pack3(XC[r_], c0_, c1_, c2_);                                   \
        *(u32x4*)p_        = (u32x4){a0_, a1_, a2_, c0_};               \
        *(u32x2*)(p_ + 16) = (u32x2){c1_, c2_};                         \
    }

#define LOAD4C(g, XA, XC)                                               \
    _Pragma("unroll")                                                   \
    for (int r_ = 0; r_ < 4; ++r_) {                                    \
        const unsigned char* p_ = cb + (size_t)((g) * 4 - 8 + r_) * 1536 + lane24; \
        const u32x4 d4_ = *(const u32x4*)p_;                            \
        const u32x2 d2_ = *(const u32x2*)(p_ + 16);                     \
        XA[r_] = unpack3(d4_.x, d4_.y, d4_.z);                          \
        XC[r_] = unpack3(d4_.w, d2_.x, d2_.y);                          \
    }

#define ARCH4(XA, XC)                                                   \
    _Pragma("unroll")                                                   \
    for (int r_ = 0; r_ < 4; ++r_) { XA[r_] = aA[r_]; XC[r_] = aC[r_]; }

#define STAGE4(XA, XC)                                                  \
    _Pragma("unroll")                                                   \
    for (int r_ = 0; r_ < 4; ++r_) {                                    \
        XA[r_] = *(const f32x4*)&stage[sb + r_][j0];                    \
        XC[r_] = *(const f32x4*)&stage[sb + r_][256 + j0];              \
    }

#define COLREDUCE()                                                      \
    { if (wave < 8) {                                                    \
          *(f32x4*)&cpart8[wave][j0]       = (f32x4){cac[0],cac[1],cac[2],cac[3]}; \
          *(f32x4*)&cpart8[wave][256 + j0] = (f32x4){cac[4],cac[5],cac[6],cac[7]}; \
      }                                                                  \
      __syncthreads();                                                   \
      if (wave >= 8) {                                                   \
          f32x4 t0 = *(f32x4*)&cpart8[wave - 8][j0];                     \
          f32x4 t1 = *(f32x4*)&cpart8[wave - 8][256 + j0];               \
          t0 += (f32x4){cac[0],cac[1],cac[2],cac[3]};                    \
          t1 += (f32x4){cac[4],cac[5],cac[6],cac[7]};                    \
          *(f32x4*)&cpart8[wave - 8][j0]       = t0;                     \
          *(f32x4*)&cpart8[wave - 8][256 + j0] = t1;                     \
      }                                                                  \
      __syncthreads();                                                   \
      if (tid < N) {                                                     \
          float ss = 0.f;                                                \
          _Pragma("unroll")                                              \
          for (int p = 0; p < 8; ++p) ss += cpart8[p][tid];              \
          v_s[tid] += LOG2(fmaxf(ss, 1e-37f));                           \
      }                                                                  \
      __syncthreads(); }

    f32x4 aA[4], aC[4];            // VGPR archive: rows row0+0..3 (raw x)

    if (tid < N) { u_s[tid] = 0.0f; v_s[tid] = 0.0f; }
    __syncthreads();

    // --- iteration 0: full fp32 read (NT); fill archive/stage; emit packed --
    {
        const float vz[8] = {0.f,0.f,0.f,0.f,0.f,0.f,0.f,0.f};
        float cac[8] = {0.f,0.f,0.f,0.f,0.f,0.f,0.f,0.f};
        f32x4 xa[4], xc[4];
        LOAD4(0, xa, xc)
        #pragma unroll
        for (int r = 0; r < 4; ++r) { aA[r] = xa[r]; aC[r] = xc[r]; }
        proc4<true>(xa, xc, vz, cac, u_s, row0, lane);
        LOAD4(1, xa, xc)
        #pragma unroll
        for (int r = 0; r < 4; ++r) {
            *(f32x4*)&stage[sb + r][j0]       = xa[r];
            *(f32x4*)&stage[sb + r][256 + j0] = xc[r];
        }
        proc4<true>(xa, xc, vz, cac, u_s, row0 + 4, lane);
        #pragma unroll 1
        for (int g = 2; g < 8; ++g) {
            LOAD4(g, xa, xc)
            PACK4(g, xa, xc)
            proc4<true>(xa, xc, vz, cac, u_s, row0 + g * 4, lane);
        }
        COLREDUCE()
    }

    // --- iterations 1..20: resident + compressed re-read, SIMD-staggered ----
    #pragma unroll 1
    for (int it = 1; it < NITER; ++it) {
        const f32x4 va = *(const f32x4*)&v_s[j0];
        const f32x4 vb = *(const f32x4*)&v_s[256 + j0];
        const float vl[8] = {va.x, va.y, va.z, va.w, vb.x, vb.y, vb.z, vb.w};
        float cac[8] = {0.f,0.f,0.f,0.f,0.f,0.f,0.f,0.f};
        f32x4 xa[4], xc[4];

        #pragma unroll 1
        for (int p = 0; p < 8; ++p) {
            const int g = (p + srot2) & 7;   // wave-uniform branch
            if (g == 0) {
                ARCH4(xa, xc)
                proc4<false>(xa, xc, vl, cac, u_s, row0, lane);
            } else if (g == 1) {
                STAGE4(xa, xc)
                proc4<false>(xa, xc, vl, cac, u_s, row0 + 4, lane);
            } else {
                LOAD4C(g, xa, xc)
                proc4<false>(xa, xc, vl, cac, u_s, row0 + g * 4, lane);
            }
        }
        COLREDUCE()
    }

    // --- output from COMPRESSED data, descending groups (anti-clobber) ------
    // g7..g2: read own compressed rows (untouched bytes), write output rows
    // whose bytes hold only already-consumed compressed data. g1/g0 last.
    {
        const f32x4 va = *(const f32x4*)&v_s[j0];
        const f32x4 vb = *(const f32x4*)&v_s[256 + j0];
        const float vl[8] = {va.x, va.y, va.z, va.w, vb.x, vb.y, vb.z, vb.w};
        float* __restrict__ ob = out + base;
        f32x4 xa[4], xc[4];
        #pragma unroll 1
        for (int g = 7; g >= 2; --g) {
            LOAD4C(g, xa, xc)
            out4(xa, xc, vl, u_s, row0 + g * 4, ob, j0);
        }
        STAGE4(xa, xc)
        out4(xa, xc, vl, u_s, row0 + 4, ob, j0);
        ARCH4(xa, xc)
        out4(xa, xc, vl, u_s, row0, ob, j0);
    }
}

extern "C" void kernel_launch(void* const* d_in, const int* in_sizes, int n_in,
                              void* d_out, int out_size, void* d_ws, size_t ws_size,
                              hipStream_t stream) {
    const float* x = (const float*)d_in[0];
    float* out = (float*)d_out;
    const int nmat = in_sizes[0] / (N * N);   // 256
    sinkhorn_kernel<<<nmat, 1024, 0, stream>>>(x, out);
}